// Round 11
// baseline (217.228 us; speedup 1.0000x reference)
//
#include <hip/hip_runtime.h>
#include <hip/hip_bf16.h>

#define B_N 16384
#define TAU 0.25f
#define GS 68     // G leading dim (floats); 16B-aligned rows
#define YS 133    // Y leading dim (floats); ODD -> scalar access conflict-free

typedef float f32x4 __attribute__((ext_vector_type(4)));
typedef short s16x8 __attribute__((ext_vector_type(8)));

__device__ __forceinline__ void gl_lds16(const void* g, void* l) {
    __builtin_amdgcn_global_load_lds(
        (const __attribute__((address_space(1))) void*)g,
        (__attribute__((address_space(3))) void*)l, 16, 0, 0);
}

__device__ __forceinline__ unsigned short bf16_bits(float v) {
    __hip_bfloat16 h = __float2bfloat16(v);
    return *reinterpret_cast<unsigned short*>(&h);
}

// ---------------------------------------------------------------------------
// Kernel 1 (merged): blocks 0..63 = per-cluster prep; blocks 64..319 = convert.
// (byte-identical to R9/R10 — frozen for attribution)
// ---------------------------------------------------------------------------
__global__ __launch_bounds__(256) void prep_convert(const float* __restrict__ x,
                                                    const float* __restrict__ D,
                                                    unsigned short* __restrict__ xh,
                                                    float* __restrict__ nrm,
                                                    float* __restrict__ Qg,
                                                    unsigned short* __restrict__ Bht,
                                                    float* __restrict__ out) {
    const int t = threadIdx.x;

    if (blockIdx.x >= 64) {
        // ---------------- convert path ----------------
        const int gid = (blockIdx.x - 64) * 256 + t;   // 0..65535 quarter-rows
        if (gid == 0) out[0] = 0.0f;
        const size_t base = (size_t)gid * 32;
        float s = 0.0f;
        #pragma unroll
        for (int c = 0; c < 8; ++c) {
            const f32x4 v = ((const f32x4*)(x + base))[c];
            s += v.x * v.x + v.y * v.y + v.z * v.z + v.w * v.w;
            ushort4 h;
            h.x = bf16_bits(v.x); h.y = bf16_bits(v.y);
            h.z = bf16_bits(v.z); h.w = bf16_bits(v.w);
            ((ushort4*)(xh + base))[c] = h;
        }
        s += __shfl_xor(s, 1, 64);
        s += __shfl_xor(s, 2, 64);
        if ((gid & 3) == 0) nrm[gid >> 2] = s;
        return;
    }

    // ---------------- prep path ----------------
    __shared__ float Y[64 * YS];                      // D^T -> Q^T (in place)
    __shared__ __align__(16) float G[64 * GS + 64];   // gram -> L; tail = 1/L[i][i]
    __shared__ __align__(16) float Lti[8 * 8 * 8];    // 8x8 diag-block inverses
    const int n = blockIdx.x;
    const float* Dn = D + (size_t)n * 8192;

    // Phase A: Y[j][c] = Dn[c][j]  (coalesced f32x4 global reads; <=2-way LDS)
    for (int e4 = t; e4 < 2048; e4 += 256) {
        const int c = e4 >> 4, j4 = (e4 & 15) * 4;
        const f32x4 v = ((const f32x4*)Dn)[e4];
        Y[(j4 + 0) * YS + c] = v.x;
        Y[(j4 + 1) * YS + c] = v.y;
        Y[(j4 + 2) * YS + c] = v.z;
        Y[(j4 + 3) * YS + c] = v.w;
    }

    // Phase B: gram from global (L1-hot, no LDS bank traffic)
    {
        const int a0 = (t & 15) * 4, b0 = (t >> 4) * 4;
        float acc[4][4] = {};
        #pragma unroll 4
        for (int i = 0; i < 128; ++i) {
            const f32x4 av = *(const f32x4*)(Dn + i * 64 + a0);
            const f32x4 bv = *(const f32x4*)(Dn + i * 64 + b0);
            const float aa[4] = {av.x, av.y, av.z, av.w};
            const float bb[4] = {bv.x, bv.y, bv.z, bv.w};
            #pragma unroll
            for (int p = 0; p < 4; ++p)
                #pragma unroll
                for (int q = 0; q < 4; ++q) acc[p][q] = fmaf(aa[p], bb[q], acc[p][q]);
        }
        #pragma unroll
        for (int p = 0; p < 4; ++p)
            #pragma unroll
            for (int q = 0; q < 4; ++q) G[(a0 + p) * GS + b0 + q] = acc[p][q];
    }
    __syncthreads();

    // Phase C: blocked Cholesky, register-resident 8x8 panel factors
    for (int p8 = 0; p8 < 8; ++p8) {
        const int pb = p8 * 8;
        if (t < 64) {   // wave 0
            const int lane = t;
            const f32x4 v0 = *(const f32x4*)&G[lane * GS + pb];
            const f32x4 v1 = *(const f32x4*)&G[lane * GS + pb + 4];
            float g[8] = {v0.x, v0.y, v0.z, v0.w, v1.x, v1.y, v1.z, v1.w};
            #pragma unroll
            for (int kk = 0; kk < 8; ++kk) {
                const int k = pb + kk;
                const float dk = __shfl(g[kk], k, 64);
                const float rinv = 1.0f / sqrtf(dk);
                const float lik = g[kk] * rinv;
                g[kk] = lik;
                if (lane == 0) G[64 * GS + k] = rinv;
                #pragma unroll
                for (int jj = kk + 1; jj < 8; ++jj) {
                    const float ljk = __shfl(lik, pb + jj, 64);
                    g[jj] -= lik * ljk;
                }
            }
            *(f32x4*)&G[lane * GS + pb]     = (f32x4){g[0], g[1], g[2], g[3]};
            *(f32x4*)&G[lane * GS + pb + 4] = (f32x4){g[4], g[5], g[6], g[7]};
        }
        __syncthreads();
        const int base = pb + 8;
        if (base < 64) {   // rank-8 trailing update, all 256 threads
            for (int i = base + (t >> 5); i < 64; i += 8) {
                const f32x4 Li0 = *(const f32x4*)&G[i * GS + pb];
                const f32x4 Li1 = *(const f32x4*)&G[i * GS + pb + 4];
                for (int j = base + (t & 31); j < 64; j += 32) {
                    const f32x4 Lj0 = *(const f32x4*)&G[j * GS + pb];
                    const f32x4 Lj1 = *(const f32x4*)&G[j * GS + pb + 4];
                    float s = G[i * GS + j];
                    s -= Li0.x * Lj0.x + Li0.y * Lj0.y + Li0.z * Lj0.z + Li0.w * Lj0.w;
                    s -= Li1.x * Lj1.x + Li1.y * Lj1.y + Li1.z * Lj1.z + Li1.w * Lj1.w;
                    G[i * GS + j] = s;
                }
            }
        }
        __syncthreads();
    }

    // Phase D: invert 8x8 diagonal blocks independently. t<64: block bi, col c.
    if (t < 64) {
        const int bi = t >> 3, c = t & 7;
        const int base = bi * 8;
        float m[8];
        #pragma unroll
        for (int r = 0; r < 8; ++r) {
            float s = (r == c) ? 1.0f : 0.0f;
            #pragma unroll
            for (int k = 0; k < r; ++k)
                s -= G[(base + r) * GS + base + k] * m[k];
            m[r] = s * G[64 * GS + base + r];
        }
        #pragma unroll
        for (int r = 0; r < 8; ++r) Lti[(base + r) * 8 + c] = m[r];
    }
    __syncthreads();

    // Phase E: Q^T = L^{-1} D^T, block forward substitution; thread = column c.
    if (t < 128) {
        const int c = t;
        for (int i = 0; i < 8; ++i) {
            float Tv[8];
            #pragma unroll
            for (int r = 0; r < 8; ++r) Tv[r] = Y[(i * 8 + r) * YS + c];
            for (int k = 0; k < i; ++k) {
                #pragma unroll
                for (int kk = 0; kk < 8; ++kk) {
                    const float z = Y[(k * 8 + kk) * YS + c];
                    #pragma unroll
                    for (int r = 0; r < 8; ++r)
                        Tv[r] -= G[(i * 8 + r) * GS + k * 8 + kk] * z;
                }
            }
            #pragma unroll
            for (int r = 0; r < 8; ++r) {
                float z = 0.0f;
                #pragma unroll
                for (int rp = 0; rp <= r; ++rp)
                    z += Lti[(i * 8 + r) * 8 + rp] * Tv[rp];
                Y[(i * 8 + r) * YS + c] = z;
            }
        }
    }
    __syncthreads();

    // Phase F: outputs. Y[j][i] = Q^T.
    for (int e = t; e < 8192; e += 256) {
        const int j = e >> 7, i = e & 127;
        Bht[((size_t)n * 64 + j) * 128 + i] = bf16_bits(Y[j * YS + i]);
    }
    for (int e = t; e < 8192; e += 256) {
        const int i = e >> 6, j = e & 63;
        Qg[(size_t)n * 8192 + e] = Y[j * YS + i];
    }
}

// ---------------------------------------------------------------------------
// Kernel 2 (fused v2): scores + argmax + loss + rescore.
// 256 blocks x 64 samples. Fixes R10's latency structure:
//  - B double-buffered (2x32 KB), DMA for tile it+1 kicked at ITERATION START
//    into the idle buffer -> end-barrier drain waits on an ~800-cyc-old DMA.
//  - ONE barrier per iteration (R10 had two).
//  - wave = (cluster, k-half) quadrant -> B-frag reads unique per wave
//    (8 ds_read_b128/iter, was 16 redundant); cross-wave k-sum via ds_add_f32.
//  - A-frags (full m=64) register-resident; all 8 MFMA chains issued before
//    the epilogue for ILP at 1 wave/SIMD.
// LDS = 80 KB exactly: A(16, ->St after) + B0(32) + B1(32); flags alias B0.
// ---------------------------------------------------------------------------
__global__ __launch_bounds__(256) void gemm_argmax(const unsigned short* __restrict__ xh,
                                                   const unsigned short* __restrict__ Bht,
                                                   const float* __restrict__ nrm,
                                                   const float* __restrict__ x,
                                                   const float* __restrict__ Qg,
                                                   float* __restrict__ out) {
    __shared__ __align__(16) unsigned char lds_raw[81920];
    unsigned short* ldsA  = (unsigned short*)lds_raw;             // 16 KB
    unsigned short* ldsB0 = (unsigned short*)(lds_raw + 16384);   // 32 KB
    unsigned short* ldsB1 = (unsigned short*)(lds_raw + 49152);   // 32 KB
    float* St   = (float*)lds_raw;                                // 64x64, aliases A
    int*   sflags = (int*)(lds_raw + 16384);                      // aliases B0 (dead)
    int*   scnt   = (int*)(lds_raw + 16384 + 256);
    float* ssum   = (float*)(lds_raw + 16384 + 260);
    float* scorr  = (float*)(lds_raw + 16384 + 272);

    const int t = threadIdx.x, w = t >> 6, lane = t & 63;
    const int b0 = blockIdx.x * 64;
    const int cl = w >> 1;    // cluster within B-tile (0/1)
    const int ch = w & 1;     // k-half (0/1)

    // ---- stage A (64x128) + kick B tile 0 ----
    {
        const int rl = lane >> 4, p = lane & 15;
        #pragma unroll
        for (int q = 0; q < 4; ++q) {
            const int row = w * 16 + q * 4 + rl;
            const int c = p ^ (row & 15);
            gl_lds16(xh + (size_t)(b0 + row) * 128 + c * 8,
                     &ldsA[(w * 16 + q * 4) * 128]);
        }
        #pragma unroll
        for (int q = 0; q < 8; ++q) {
            const int row = w * 32 + q * 4 + rl;
            const int c = p ^ (row & 15);
            gl_lds16(Bht + (size_t)row * 128 + c * 8,
                     &ldsB0[(w * 32 + q * 4) * 128]);
        }
    }
    __syncthreads();   // A + B0 staged

    // ---- A-frags register-resident: full m (4 tiles x 4 ks = 64 VGPRs) ----
    s16x8 af[4][4];
    #pragma unroll
    for (int mt = 0; mt < 4; ++mt) {
        const int r = mt * 16 + (lane & 15);
        #pragma unroll
        for (int ks = 0; ks < 4; ++ks) {
            const int p = (ks * 4 + (lane >> 4)) ^ (r & 15);
            af[mt][ks] = *(const s16x8*)&ldsA[r * 128 + p * 8];
        }
    }
    __syncthreads();   // ldsA reads done -> St may overwrite

    for (int e = t; e < 4096; e += 256) St[e] = 0.0f;
    __syncthreads();   // St zeroed

    #pragma unroll 1
    for (int it = 0; it < 32; ++it) {
        unsigned short* cur = (it & 1) ? ldsB1 : ldsB0;
        unsigned short* nxt = (it & 1) ? ldsB0 : ldsB1;

        // ---- early kick: DMA tile it+1 into the idle buffer ----
        if (it < 31) {
            const int rl = lane >> 4, p = lane & 15;
            #pragma unroll
            for (int q = 0; q < 8; ++q) {
                const int row = w * 32 + q * 4 + rl;
                const int c = p ^ (row & 15);
                gl_lds16(Bht + (size_t)((it + 1) * 128 + row) * 128 + c * 8,
                         &nxt[(w * 32 + q * 4) * 128]);
            }
        }

        // ---- this wave's unique B-frags: cluster cl, k-half ch ----
        s16x8 bf[2][4];
        #pragma unroll
        for (int nt = 0; nt < 2; ++nt) {
            const int r = cl * 64 + ch * 32 + nt * 16 + (lane & 15);
            #pragma unroll
            for (int ks = 0; ks < 4; ++ks) {
                const int p = (ks * 4 + (lane >> 4)) ^ (r & 15);
                bf[nt][ks] = *(const s16x8*)&cur[r * 128 + p * 8];
            }
        }

        // ---- 32 MFMAs, 8 independent chains ----
        f32x4 acc[4][2];
        #pragma unroll
        for (int mt = 0; mt < 4; ++mt)
            #pragma unroll
            for (int nt = 0; nt < 2; ++nt) acc[mt][nt] = (f32x4){0.f, 0.f, 0.f, 0.f};
        #pragma unroll
        for (int ks = 0; ks < 4; ++ks)
            #pragma unroll
            for (int mt = 0; mt < 4; ++mt)
                #pragma unroll
                for (int nt = 0; nt < 2; ++nt)
                    acc[mt][nt] = __builtin_amdgcn_mfma_f32_16x16x32_bf16(
                        af[mt][ks], bf[nt][ks], acc[mt][nt], 0, 0, 0);

        // ---- epilogue: partial squared-sum over this wave's 32 k ----
        const int nc = it * 2 + cl;
        #pragma unroll
        for (int mt = 0; mt < 4; ++mt) {
            #pragma unroll
            for (int rg = 0; rg < 4; ++rg) {
                const float v0 = acc[mt][0][rg], v1 = acc[mt][1][rg];
                float p = v0 * v0 + v1 * v1;
                p += __shfl_xor(p, 1, 64);
                p += __shfl_xor(p, 2, 64);
                p += __shfl_xor(p, 4, 64);
                p += __shfl_xor(p, 8, 64);
                if ((lane & 15) == 0)
                    atomicAdd(&St[nc * 64 + mt * 16 + (lane >> 4) * 4 + rg], p);
            }
        }
        __syncthreads();   // drains this iter's early DMA; cur reads done
    }

    // ---- tail: flags region (aliases dead ldsB0) ----
    if (t == 0) *scnt = 0;
    if (lane == 0) scorr[w] = 0.0f;
    __syncthreads();

    // argmax + near-tie flags + loss (wave 0)
    if (t < 64) {
        float v1 = -1e30f, v2 = -1e30f;
        int n1 = 0;
        for (int n = 0; n < 64; ++n) {
            const float v = St[n * 64 + t];
            if (v > v1) { v2 = v1; v1 = v; n1 = n; }
            else v2 = fmaxf(v2, v);
        }
        out[1 + b0 + t] = (float)n1;
        if (v1 - v2 < TAU) { const int i = atomicAdd(scnt, 1); sflags[i] = t; }
        float err = nrm[b0 + t] - v1;
        for (int off = 32; off; off >>= 1) err += __shfl_xor(err, off, 64);
        if (t == 0) *ssum = err;
    }
    __syncthreads();

    // cooperative exact fp32 rescore of flagged samples
    const int nf = *scnt;
    float corr = 0.0f;
    for (int f = w; f < nf; f += 4) {
        const int s = sflags[f];
        const int b2 = b0 + s;
        const float v = St[lane * 64 + s];   // lane = cluster
        float vm = v;
        for (int off = 32; off; off >>= 1) vm = fmaxf(vm, __shfl_xor(vm, off, 64));
        unsigned long long mask = __ballot((vm - v) < TAU);
        float best = -1e30f;
        int bn = 0;
        while (mask) {
            const int nn = (int)__builtin_ctzll(mask);
            mask &= mask - 1;
            const float* Qn = Qg + (size_t)nn * 8192;
            const float* xb = x + (size_t)b2 * 128;
            float d0 = 0.0f, d1 = 0.0f, d2 = 0.0f, d3 = 0.0f;
            #pragma unroll
            for (int i = 0; i < 128; i += 4) {
                d0 = fmaf(Qn[(i + 0) * 64 + lane], xb[i + 0], d0);
                d1 = fmaf(Qn[(i + 1) * 64 + lane], xb[i + 1], d1);
                d2 = fmaf(Qn[(i + 2) * 64 + lane], xb[i + 2], d2);
                d3 = fmaf(Qn[(i + 3) * 64 + lane], xb[i + 3], d3);
            }
            const float dot = (d0 + d1) + (d2 + d3);
            float sv = dot * dot;
            for (int off = 32; off; off >>= 1) sv += __shfl_xor(sv, off, 64);
            if (sv > best) { best = sv; bn = nn; }
        }
        if (lane == 0) {
            out[1 + b2] = (float)bn;
            corr += vm - best;   // replace approx top score with exact best
        }
    }
    if (lane == 0 && corr != 0.0f) scorr[w] += corr;
    __syncthreads();
    if (t == 0)
        atomicAdd(out, *ssum + scorr[0] + scorr[1] + scorr[2] + scorr[3]);
}

// ---------------------------------------------------------------------------
extern "C" void kernel_launch(void* const* d_in, const int* in_sizes, int n_in,
                              void* d_out, int out_size, void* d_ws, size_t ws_size,
                              hipStream_t stream) {
    const float* x = (const float*)d_in[0];   // [16384, 128]
    const float* D = (const float*)d_in[1];   // [64, 128, 64]
    float* out = (float*)d_out;               // [1 + 16384]

    char* ws = (char*)d_ws;
    unsigned short* xh  = (unsigned short*)(ws);                 // 4 MB
    unsigned short* Bht = (unsigned short*)(ws + (4u << 20));    // 1 MB
    float* Qg           = (float*)(ws + (5u << 20));             // 2 MB
    float* nrm          = (float*)(ws + (11u << 20));            // 64 KB

    prep_convert<<<320, 256, 0, stream>>>(x, D, xh, nrm, Qg, Bht, out);
    gemm_argmax<<<256, 256, 0, stream>>>(xh, Bht, nrm, x, Qg, out);
}

// Round 12
// 172.943 us; speedup vs baseline: 1.2561x; 1.2561x over previous
//
#include <hip/hip_runtime.h>
#include <hip/hip_bf16.h>

#define B_N 16384
#define TAU 0.25f
#define GS 68     // G leading dim (floats); 16B-aligned rows
#define YS 133    // Y leading dim (floats); ODD -> scalar access conflict-free

typedef float f32x4 __attribute__((ext_vector_type(4)));
typedef short s16x8 __attribute__((ext_vector_type(8)));

__device__ __forceinline__ unsigned short bf16_bits(float v) {
    __hip_bfloat16 h = __float2bfloat16(v);
    return *reinterpret_cast<unsigned short*>(&h);
}

// ---------------------------------------------------------------------------
// Kernel 1 (merged): blocks 0..63 = per-cluster prep; blocks 64..319 = convert.
// (byte-identical to R9-R11 — frozen for attribution)
// ---------------------------------------------------------------------------
__global__ __launch_bounds__(256) void prep_convert(const float* __restrict__ x,
                                                    const float* __restrict__ D,
                                                    unsigned short* __restrict__ xh,
                                                    float* __restrict__ nrm,
                                                    float* __restrict__ Qg,
                                                    unsigned short* __restrict__ Bht,
                                                    float* __restrict__ out) {
    const int t = threadIdx.x;

    if (blockIdx.x >= 64) {
        // ---------------- convert path ----------------
        const int gid = (blockIdx.x - 64) * 256 + t;   // 0..65535 quarter-rows
        if (gid == 0) out[0] = 0.0f;
        const size_t base = (size_t)gid * 32;
        float s = 0.0f;
        #pragma unroll
        for (int c = 0; c < 8; ++c) {
            const f32x4 v = ((const f32x4*)(x + base))[c];
            s += v.x * v.x + v.y * v.y + v.z * v.z + v.w * v.w;
            ushort4 h;
            h.x = bf16_bits(v.x); h.y = bf16_bits(v.y);
            h.z = bf16_bits(v.z); h.w = bf16_bits(v.w);
            ((ushort4*)(xh + base))[c] = h;
        }
        s += __shfl_xor(s, 1, 64);
        s += __shfl_xor(s, 2, 64);
        if ((gid & 3) == 0) nrm[gid >> 2] = s;
        return;
    }

    // ---------------- prep path ----------------
    __shared__ float Y[64 * YS];                      // D^T -> Q^T (in place)
    __shared__ __align__(16) float G[64 * GS + 64];   // gram -> L; tail = 1/L[i][i]
    __shared__ __align__(16) float Lti[8 * 8 * 8];    // 8x8 diag-block inverses
    const int n = blockIdx.x;
    const float* Dn = D + (size_t)n * 8192;

    // Phase A: Y[j][c] = Dn[c][j]  (coalesced f32x4 global reads; <=2-way LDS)
    for (int e4 = t; e4 < 2048; e4 += 256) {
        const int c = e4 >> 4, j4 = (e4 & 15) * 4;
        const f32x4 v = ((const f32x4*)Dn)[e4];
        Y[(j4 + 0) * YS + c] = v.x;
        Y[(j4 + 1) * YS + c] = v.y;
        Y[(j4 + 2) * YS + c] = v.z;
        Y[(j4 + 3) * YS + c] = v.w;
    }

    // Phase B: gram from global (L1-hot, no LDS bank traffic)
    {
        const int a0 = (t & 15) * 4, b0 = (t >> 4) * 4;
        float acc[4][4] = {};
        #pragma unroll 4
        for (int i = 0; i < 128; ++i) {
            const f32x4 av = *(const f32x4*)(Dn + i * 64 + a0);
            const f32x4 bv = *(const f32x4*)(Dn + i * 64 + b0);
            const float aa[4] = {av.x, av.y, av.z, av.w};
            const float bb[4] = {bv.x, bv.y, bv.z, bv.w};
            #pragma unroll
            for (int p = 0; p < 4; ++p)
                #pragma unroll
                for (int q = 0; q < 4; ++q) acc[p][q] = fmaf(aa[p], bb[q], acc[p][q]);
        }
        #pragma unroll
        for (int p = 0; p < 4; ++p)
            #pragma unroll
            for (int q = 0; q < 4; ++q) G[(a0 + p) * GS + b0 + q] = acc[p][q];
    }
    __syncthreads();

    // Phase C: blocked Cholesky, register-resident 8x8 panel factors
    for (int p8 = 0; p8 < 8; ++p8) {
        const int pb = p8 * 8;
        if (t < 64) {   // wave 0
            const int lane = t;
            const f32x4 v0 = *(const f32x4*)&G[lane * GS + pb];
            const f32x4 v1 = *(const f32x4*)&G[lane * GS + pb + 4];
            float g[8] = {v0.x, v0.y, v0.z, v0.w, v1.x, v1.y, v1.z, v1.w};
            #pragma unroll
            for (int kk = 0; kk < 8; ++kk) {
                const int k = pb + kk;
                const float dk = __shfl(g[kk], k, 64);
                const float rinv = 1.0f / sqrtf(dk);
                const float lik = g[kk] * rinv;
                g[kk] = lik;
                if (lane == 0) G[64 * GS + k] = rinv;
                #pragma unroll
                for (int jj = kk + 1; jj < 8; ++jj) {
                    const float ljk = __shfl(lik, pb + jj, 64);
                    g[jj] -= lik * ljk;
                }
            }
            *(f32x4*)&G[lane * GS + pb]     = (f32x4){g[0], g[1], g[2], g[3]};
            *(f32x4*)&G[lane * GS + pb + 4] = (f32x4){g[4], g[5], g[6], g[7]};
        }
        __syncthreads();
        const int base = pb + 8;
        if (base < 64) {   // rank-8 trailing update, all 256 threads
            for (int i = base + (t >> 5); i < 64; i += 8) {
                const f32x4 Li0 = *(const f32x4*)&G[i * GS + pb];
                const f32x4 Li1 = *(const f32x4*)&G[i * GS + pb + 4];
                for (int j = base + (t & 31); j < 64; j += 32) {
                    const f32x4 Lj0 = *(const f32x4*)&G[j * GS + pb];
                    const f32x4 Lj1 = *(const f32x4*)&G[j * GS + pb + 4];
                    float s = G[i * GS + j];
                    s -= Li0.x * Lj0.x + Li0.y * Lj0.y + Li0.z * Lj0.z + Li0.w * Lj0.w;
                    s -= Li1.x * Lj1.x + Li1.y * Lj1.y + Li1.z * Lj1.z + Li1.w * Lj1.w;
                    G[i * GS + j] = s;
                }
            }
        }
        __syncthreads();
    }

    // Phase D: invert 8x8 diagonal blocks independently. t<64: block bi, col c.
    if (t < 64) {
        const int bi = t >> 3, c = t & 7;
        const int base = bi * 8;
        float m[8];
        #pragma unroll
        for (int r = 0; r < 8; ++r) {
            float s = (r == c) ? 1.0f : 0.0f;
            #pragma unroll
            for (int k = 0; k < r; ++k)
                s -= G[(base + r) * GS + base + k] * m[k];
            m[r] = s * G[64 * GS + base + r];
        }
        #pragma unroll
        for (int r = 0; r < 8; ++r) Lti[(base + r) * 8 + c] = m[r];
    }
    __syncthreads();

    // Phase E: Q^T = L^{-1} D^T, block forward substitution; thread = column c.
    if (t < 128) {
        const int c = t;
        for (int i = 0; i < 8; ++i) {
            float Tv[8];
            #pragma unroll
            for (int r = 0; r < 8; ++r) Tv[r] = Y[(i * 8 + r) * YS + c];
            for (int k = 0; k < i; ++k) {
                #pragma unroll
                for (int kk = 0; kk < 8; ++kk) {
                    const float z = Y[(k * 8 + kk) * YS + c];
                    #pragma unroll
                    for (int r = 0; r < 8; ++r)
                        Tv[r] -= G[(i * 8 + r) * GS + k * 8 + kk] * z;
                }
            }
            #pragma unroll
            for (int r = 0; r < 8; ++r) {
                float z = 0.0f;
                #pragma unroll
                for (int rp = 0; rp <= r; ++rp)
                    z += Lti[(i * 8 + r) * 8 + rp] * Tv[rp];
                Y[(i * 8 + r) * YS + c] = z;
            }
        }
    }
    __syncthreads();

    // Phase F: outputs. Y[j][i] = Q^T.
    for (int e = t; e < 8192; e += 256) {
        const int j = e >> 7, i = e & 127;
        Bht[((size_t)n * 64 + j) * 128 + i] = bf16_bits(Y[j * YS + i]);
    }
    for (int e = t; e < 8192; e += 256) {
        const int i = e >> 6, j = e & 63;
        Qg[(size_t)n * 8192 + e] = Y[j * YS + i];
    }
}

// ---------------------------------------------------------------------------
// Kernel 2 (fused v3): BARRIER-FREE GEMM + argmax + loss + rescore.
// 256 blocks x 64 samples; wave w owns clusters w*16..w*16+15 for ALL 64
// samples. A- and B-fragments are loaded DIRECTLY from global (16B-aligned
// dwordx4, L1/L2-resident) — no LDS staging, no __syncthreads until the
// single pre-argmax barrier. R10/R11 showed per-tile barriers at 1 block/CU
// are latency-doomed; here each wave pipelines freely under vmcnt.
// B-frags double-buffered in registers (load pass p+1 during pass p MFMAs).
// LDS: St[64][65] scores only (16.6 KB).
// ---------------------------------------------------------------------------
__global__ __launch_bounds__(256, 1) void gemm_argmax(
        const unsigned short* __restrict__ xh,
        const unsigned short* __restrict__ Bht,
        const float* __restrict__ nrm,
        const float* __restrict__ x,
        const float* __restrict__ Qg,
        float* __restrict__ out) {
    __shared__ float St[64 * 65];   // [sample][cluster]
    __shared__ int sflags[64];
    __shared__ int scnt;
    __shared__ float ssum;
    __shared__ float scorr[4];

    const int t = threadIdx.x, w = t >> 6, lane = t & 63;
    const int b0 = blockIdx.x * 64;
    const int c0 = w * 16;          // this wave's first cluster
    const int lm = lane & 15;       // fragment row/col lane
    const int lg = lane >> 4;       // k-group
    if (t == 0) scnt = 0;
    if (lane == 0) scorr[w] = 0.0f;

    // ---- A-fragments for all 64 samples, straight from global (64 VGPRs) ----
    s16x8 af[4][4];   // [mt][ks]
    #pragma unroll
    for (int mt = 0; mt < 4; ++mt)
        #pragma unroll
        for (int ks = 0; ks < 4; ++ks)
            af[mt][ks] = *(const s16x8*)(xh +
                (size_t)(b0 + mt * 16 + lm) * 128 + ks * 32 + lg * 8);

    // ---- B-frag loader: cluster n, j-half nh -> 8 dwordx4 loads ----
    #define LOAD_B(dst, n, nh)                                              \
        _Pragma("unroll")                                                   \
        for (int nt = 0; nt < 2; ++nt)                                      \
            _Pragma("unroll")                                               \
            for (int ks = 0; ks < 4; ++ks)                                  \
                dst[nt][ks] = *(const s16x8*)(Bht +                         \
                    ((size_t)(n) * 64 + (nh) * 32 + nt * 16 + lm) * 128 +   \
                    ks * 32 + lg * 8);

    #define MFMA_P(ps, bfr)                                                 \
        {                                                                   \
            f32x4 acc[4][2];                                                \
            _Pragma("unroll")                                               \
            for (int mt = 0; mt < 4; ++mt)                                  \
                _Pragma("unroll")                                           \
                for (int nt = 0; nt < 2; ++nt)                              \
                    acc[mt][nt] = (f32x4){0.f, 0.f, 0.f, 0.f};              \
            _Pragma("unroll")                                               \
            for (int ks = 0; ks < 4; ++ks)                                  \
                _Pragma("unroll")                                           \
                for (int mt = 0; mt < 4; ++mt)                              \
                    _Pragma("unroll")                                       \
                    for (int nt = 0; nt < 2; ++nt)                          \
                        acc[mt][nt] = __builtin_amdgcn_mfma_f32_16x16x32_bf16( \
                            af[mt][ks], bfr[nt][ks], acc[mt][nt], 0, 0, 0); \
            _Pragma("unroll")                                               \
            for (int mt = 0; mt < 4; ++mt)                                  \
                _Pragma("unroll")                                           \
                for (int rg = 0; rg < 4; ++rg) {                            \
                    const float q0 = acc[mt][0][rg], q1 = acc[mt][1][rg];   \
                    ps[mt][rg] = fmaf(q0, q0, fmaf(q1, q1, ps[mt][rg]));    \
                }                                                           \
        }

    s16x8 bfA[2][4], bfB[2][4];
    LOAD_B(bfA, c0, 0);

    #pragma unroll 1
    for (int c = 0; c < 16; ++c) {
        const int n = c0 + c;
        float ps[4][4];
        #pragma unroll
        for (int mt = 0; mt < 4; ++mt)
            #pragma unroll
            for (int rg = 0; rg < 4; ++rg) ps[mt][rg] = 0.0f;

        LOAD_B(bfB, n, 1);          // prefetch j-half 1
        MFMA_P(ps, bfA);            // compute j-half 0
        if (c < 15) { LOAD_B(bfA, n + 1, 0); }   // prefetch next cluster
        MFMA_P(ps, bfB);            // compute j-half 1

        // reduce over the 16 col-lanes; lanes lm==0 hold 4 samples x 4 regs
        #pragma unroll
        for (int mt = 0; mt < 4; ++mt)
            #pragma unroll
            for (int rg = 0; rg < 4; ++rg) {
                float p = ps[mt][rg];
                p += __shfl_xor(p, 1, 64);
                p += __shfl_xor(p, 2, 64);
                p += __shfl_xor(p, 4, 64);
                p += __shfl_xor(p, 8, 64);
                if (lm == 0)
                    St[(mt * 16 + lg * 4 + rg) * 65 + n] = p;
            }
    }
    #undef LOAD_B
    #undef MFMA_P

    __syncthreads();   // the only barrier before the tail

    // ---- argmax + near-tie flags + loss (threads 0..63 = samples) ----
    if (t < 64) {
        float v1 = -1e30f, v2 = -1e30f;
        int n1 = 0;
        for (int n = 0; n < 64; ++n) {
            const float v = St[t * 65 + n];
            if (v > v1) { v2 = v1; v1 = v; n1 = n; }
            else v2 = fmaxf(v2, v);
        }
        out[1 + b0 + t] = (float)n1;
        if (v1 - v2 < TAU) { const int i = atomicAdd(&scnt, 1); sflags[i] = t; }
        float err = nrm[b0 + t] - v1;
        for (int off = 32; off; off >>= 1) err += __shfl_xor(err, off, 64);
        if (t == 0) ssum = err;
    }
    __syncthreads();

    // ---- cooperative exact fp32 rescore of flagged samples ----
    const int nf = scnt;
    float corr = 0.0f;
    for (int f = w; f < nf; f += 4) {
        const int s = sflags[f];
        const int b2 = b0 + s;
        const float v = St[s * 65 + lane];   // lane = cluster
        float vm = v;
        for (int off = 32; off; off >>= 1) vm = fmaxf(vm, __shfl_xor(vm, off, 64));
        unsigned long long mask = __ballot((vm - v) < TAU);
        float best = -1e30f;
        int bn = 0;
        while (mask) {
            const int nn = (int)__builtin_ctzll(mask);
            mask &= mask - 1;
            const float* Qn = Qg + (size_t)nn * 8192;
            const float* xb = x + (size_t)b2 * 128;
            float d0 = 0.0f, d1 = 0.0f, d2 = 0.0f, d3 = 0.0f;
            #pragma unroll
            for (int i = 0; i < 128; i += 4) {
                d0 = fmaf(Qn[(i + 0) * 64 + lane], xb[i + 0], d0);
                d1 = fmaf(Qn[(i + 1) * 64 + lane], xb[i + 1], d1);
                d2 = fmaf(Qn[(i + 2) * 64 + lane], xb[i + 2], d2);
                d3 = fmaf(Qn[(i + 3) * 64 + lane], xb[i + 3], d3);
            }
            const float dot = (d0 + d1) + (d2 + d3);
            float sv = dot * dot;
            for (int off = 32; off; off >>= 1) sv += __shfl_xor(sv, off, 64);
            if (sv > best) { best = sv; bn = nn; }
        }
        if (lane == 0) {
            out[1 + b2] = (float)bn;
            corr += vm - best;   // replace approx top score with exact best
        }
    }
    if (lane == 0 && corr != 0.0f) scorr[w] += corr;
    __syncthreads();
    if (t == 0)
        atomicAdd(out, ssum + scorr[0] + scorr[1] + scorr[2] + scorr[3]);
}

// ---------------------------------------------------------------------------
extern "C" void kernel_launch(void* const* d_in, const int* in_sizes, int n_in,
                              void* d_out, int out_size, void* d_ws, size_t ws_size,
                              hipStream_t stream) {
    const float* x = (const float*)d_in[0];   // [16384, 128]
    const float* D = (const float*)d_in[1];   // [64, 128, 64]
    float* out = (float*)d_out;               // [1 + 16384]

    char* ws = (char*)d_ws;
    unsigned short* xh  = (unsigned short*)(ws);                 // 4 MB
    unsigned short* Bht = (unsigned short*)(ws + (4u << 20));    // 1 MB
    float* Qg           = (float*)(ws + (5u << 20));             // 2 MB
    float* nrm          = (float*)(ws + (11u << 20));            // 64 KB

    prep_convert<<<320, 256, 0, stream>>>(x, D, xh, nrm, Qg, Bht, out);
    gemm_argmax<<<256, 256, 0, stream>>>(xh, Bht, nrm, x, Qg, out);
}